// Round 4
// baseline (1511.499 us; speedup 1.0000x reference)
//
#include <hip/hip_runtime.h>
#include <math.h>

#define B_  2
#define W_  2048
#define C_  1024
#define NH_ 16
#define KD_ 64

// ---------------------------------------------------------------------------
// XOR-swizzled 64-float-wide tiles, flat storage. float4 chunk of row r,
// col c stored at chunk slot (c>>2) ^ ((r>>SH)&7). SH=2 for micro-row-stride
// 4 readers (attention), SH=3 for stride 8 (gemm): makes the strided-row
// b128 reads 2-way (free) instead of 4/8-way.
// ---------------------------------------------------------------------------
__device__ __forceinline__ int swz2(int r, int c) {
    return (r << 6) + ((((c >> 2) ^ ((r >> 2) & 7)) << 2) | (c & 3));
}
__device__ __forceinline__ int swz3(int r, int c) {
    return (r << 6) + ((((c >> 2) ^ ((r >> 3) & 7)) << 2) | (c & 3));
}

// stage a contiguous [rows][64] fp32 block (rows*16 float4s) into swizzled LDS
__device__ __forceinline__ void stage_sw2(const float* __restrict__ src,
                                          float* dst, int tid, int nf4) {
    for (int idx = tid; idx < nf4; idx += 256) {
        int r = idx >> 4;
        int c = (idx & 15) << 2;
        *(float4*)&dst[swz2(r, c)] = *(const float4*)(src + (idx << 2));
    }
}

// ---------------------------------------------------------------------------
// GEMM NT: C[m,c] = sum_k A[m,k]*Bw[c,k] + bias[c].  128x128 tile, 8x8 micro,
// k-block 64, register-prefetched staging.  Grid (M/128, N/128).
// ---------------------------------------------------------------------------
template<int OUT_P_LAYOUT>
__global__ __launch_bounds__(256, 2)
void gemm128(const float* __restrict__ A, const float* __restrict__ Bw,
             const float* __restrict__ bias, float* __restrict__ Cout)
{
    __shared__ float As[8192];   // [128][64] swz3
    __shared__ float Bs[8192];
    const int tid = threadIdx.x;
    const int tx  = tid & 15, ty = tid >> 4;
    const int m0  = blockIdx.x << 7;
    const int n0  = blockIdx.y << 7;

    float4 ra[8], rb[8];
    int rr[8], cc[8];
#pragma unroll
    for (int t = 0; t < 8; ++t) {
        int idx = tid + (t << 8);
        rr[t] = idx >> 4;
        cc[t] = (idx & 15) << 2;
    }
#pragma unroll
    for (int t = 0; t < 8; ++t) {
        ra[t] = *(const float4*)(A  + (size_t)(m0 + rr[t]) * C_ + cc[t]);
        rb[t] = *(const float4*)(Bw + (size_t)(n0 + rr[t]) * C_ + cc[t]);
    }

    float acc[8][8] = {};
    for (int kb = 0; kb < 16; ++kb) {
        __syncthreads();
#pragma unroll
        for (int t = 0; t < 8; ++t) {
            *(float4*)&As[swz3(rr[t], cc[t])] = ra[t];
            *(float4*)&Bs[swz3(rr[t], cc[t])] = rb[t];
        }
        __syncthreads();
        if (kb < 15) {
            int k0 = (kb + 1) << 6;
#pragma unroll
            for (int t = 0; t < 8; ++t) {
                ra[t] = *(const float4*)(A  + (size_t)(m0 + rr[t]) * C_ + k0 + cc[t]);
                rb[t] = *(const float4*)(Bw + (size_t)(n0 + rr[t]) * C_ + k0 + cc[t]);
            }
        }
#pragma unroll
        for (int kq = 0; kq < 64; kq += 4) {
            float4 av[8], bv[8];
#pragma unroll
            for (int i = 0; i < 8; ++i) av[i] = *(const float4*)&As[swz3((ty << 3) + i, kq)];
#pragma unroll
            for (int j = 0; j < 8; ++j) bv[j] = *(const float4*)&Bs[swz3((tx << 3) + j, kq)];
#pragma unroll
            for (int i = 0; i < 8; ++i)
#pragma unroll
                for (int j = 0; j < 8; ++j)
                    acc[i][j] = fmaf(av[i].x, bv[j].x,
                                fmaf(av[i].y, bv[j].y,
                                fmaf(av[i].z, bv[j].z,
                                fmaf(av[i].w, bv[j].w, acc[i][j]))));
        }
    }

    // epilogue
#pragma unroll
    for (int h = 0; h < 2; ++h) {
        int gc = n0 + (tx << 3) + (h << 2);
        float4 bb = *(const float4*)&bias[gc];
#pragma unroll
        for (int i = 0; i < 8; ++i) {
            int gm = m0 + (ty << 3) + i;
            float4 o;
            o.x = acc[i][(h << 2) + 0] + bb.x;
            o.y = acc[i][(h << 2) + 1] + bb.y;
            o.z = acc[i][(h << 2) + 2] + bb.z;
            o.w = acc[i][(h << 2) + 3] + bb.w;
            if (OUT_P_LAYOUT) {
                int b = gm >> 11;
                int w = gm & 2047;
                int n = gc >> 6;
                int k = gc & 63;
                *(float4*)(Cout + (((size_t)(b * NH_ + n) * W_ + w) * KD_ + k)) = o;
            } else {
                *(float4*)(Cout + (size_t)gm * C_ + gc) = o;
            }
        }
    }
}

// ---------------------------------------------------------------------------
// metric_part: partial M1[k][l] = sum_{w in chunk} p[bn][w][k]*g[n][w][l]
// ---------------------------------------------------------------------------
__global__ __launch_bounds__(256, 2)
void metric_part(const float* __restrict__ p, const float* __restrict__ g,
                 float* __restrict__ part)
{
    __shared__ float Ps[32][68];
    __shared__ float Gs[32][68];
    const int ch  = blockIdx.x;
    const int bn  = blockIdx.y;
    const int n   = bn & (NH_ - 1);
    const int tid = threadIdx.x;
    const int tx  = tid & 15, ty = tid >> 4;
    const float* pb = p + (size_t)bn * W_ * KD_ + (size_t)(ch << 8) * KD_;
    const float* gb = g + (size_t)n  * W_ * KD_ + (size_t)(ch << 8) * KD_;

    float acc[4][4] = {};
    for (int w0 = 0; w0 < 256; w0 += 32) {
        __syncthreads();
#pragma unroll
        for (int q = 0; q < 2; ++q) {
            int idx = tid + (q << 8);
            int e   = idx << 2;
            int r   = e >> 6;
            int c   = e & 63;
            *(float4*)&Ps[r][c] = *(const float4*)(pb + (size_t)(w0 + r) * KD_ + c);
            *(float4*)&Gs[r][c] = *(const float4*)(gb + (size_t)(w0 + r) * KD_ + c);
        }
        __syncthreads();
#pragma unroll 8
        for (int w = 0; w < 32; ++w) {
            float4 a4 = *(const float4*)&Ps[w][ty << 2];
            float4 b4 = *(const float4*)&Gs[w][tx << 2];
            float am[4] = {a4.x, a4.y, a4.z, a4.w};
            float bm[4] = {b4.x, b4.y, b4.z, b4.w};
#pragma unroll
            for (int i = 0; i < 4; ++i)
#pragma unroll
                for (int j = 0; j < 4; ++j)
                    acc[i][j] = fmaf(am[i], bm[j], acc[i][j]);
        }
    }

    float* ob = part + (size_t)(bn * 8 + ch) * KD_ * KD_;
#pragma unroll
    for (int i = 0; i < 4; ++i) {
        float4 o; o.x = acc[i][0]; o.y = acc[i][1]; o.z = acc[i][2]; o.w = acc[i][3];
        *(float4*)(ob + ((ty << 2) + i) * KD_ + (tx << 2)) = o;
    }
}

// ---------------------------------------------------------------------------
// metric_reduce: M1 = tril(sum_ch part);  M2 = M1 @ M1^T.
// ---------------------------------------------------------------------------
__global__ __launch_bounds__(256, 2)
void metric_reduce(const float* __restrict__ part, float* __restrict__ m2)
{
    __shared__ float M1s[64][68];
    const int bn  = blockIdx.x;
    const int tid = threadIdx.x;
    const int tx  = tid & 15, ty = tid >> 4;
    const float* pb = part + (size_t)bn * 8 * KD_ * KD_;

#pragma unroll
    for (int v = 0; v < 4; ++v) {
        int f = tid + (v << 8);
        int e = f << 2;
        float4 s = *(const float4*)(pb + e);
#pragma unroll
        for (int c = 1; c < 8; ++c) {
            float4 t = *(const float4*)(pb + c * 4096 + e);
            s.x += t.x; s.y += t.y; s.z += t.z; s.w += t.w;
        }
        int k = e >> 6, l = e & 63;
        if (l + 0 > k) s.x = 0.f;
        if (l + 1 > k) s.y = 0.f;
        if (l + 2 > k) s.z = 0.f;
        if (l + 3 > k) s.w = 0.f;
        *(float4*)&M1s[k][l] = s;
    }
    __syncthreads();

    float a2[4][4] = {};
#pragma unroll
    for (int jq = 0; jq < 64; jq += 4) {
        float4 av[4], bv[4];
#pragma unroll
        for (int i = 0; i < 4; ++i) av[i] = *(const float4*)&M1s[(ty << 2) + i][jq];
#pragma unroll
        for (int j = 0; j < 4; ++j) bv[j] = *(const float4*)&M1s[(tx << 2) + j][jq];
#pragma unroll
        for (int i = 0; i < 4; ++i)
#pragma unroll
            for (int j = 0; j < 4; ++j)
                a2[i][j] += av[i].x * bv[j].x + av[i].y * bv[j].y +
                            av[i].z * bv[j].z + av[i].w * bv[j].w;
    }

    float* ob = m2 + (size_t)bn * KD_ * KD_;
#pragma unroll
    for (int i = 0; i < 4; ++i) {
        float4 o; o.x = a2[i][0]; o.y = a2[i][1]; o.z = a2[i][2]; o.w = a2[i][3];
        *(float4*)(ob + ((ty << 2) + i) * KD_ + (tx << 2)) = o;
    }
}

// ---------------------------------------------------------------------------
// Fused Q-gen + causal flash attention per (b,n).
// q-tile 128, k-tile 64, 256 threads, micro 8x4.
// Prologue: Q = P_qtile @ M2 * 0.125 computed in-block (Pq staged in Es,
// M2 in Ks -> zero extra LDS), written to Qs.
// Grid: 512 blocks 1D, descending-cost: qt = 15-(bid>>5), bn = bid&31.
// Out: nudged [b][w][n*64+k] ([4096][1024]).
// ---------------------------------------------------------------------------
__global__ __launch_bounds__(256, 2)
void attn_k2(const float* __restrict__ p, const float* __restrict__ m2,
             float* __restrict__ nud)
{
    __shared__ float Qs[8192];   // [128][64] swz2
    __shared__ float Ks[4096];   // [64][64]  swz2
    __shared__ float Es[8192];   // [128][64] swz2
    const int bid = blockIdx.x;
    const int bn  = bid & 31;
    const int qt  = 15 - (bid >> 5);
    const int b   = bn >> 4, n = bn & 15;
    const int tid = threadIdx.x;
    const int tx  = tid & 15, ty = tid >> 4;
    const float* pb = p + (size_t)bn * W_ * KD_;
    const float* qb = pb + (size_t)(qt << 7) * KD_;

    // ---- prologue: stage Pq -> Es, M2 -> Ks; compute Q -> Qs -------------
    stage_sw2(qb, Es, tid, 2048);
    stage_sw2(m2 + (size_t)bn * KD_ * KD_, Ks, tid, 1024);
    __syncthreads();
    {
        float qacc[8][4] = {};
#pragma unroll
        for (int kq = 0; kq < 64; kq += 4) {
            float4 av[8], bm[4];
#pragma unroll
            for (int i = 0; i < 8; ++i) av[i] = *(const float4*)&Es[swz2((ty << 3) + i, kq)];
#pragma unroll
            for (int kk = 0; kk < 4; ++kk) bm[kk] = *(const float4*)&Ks[swz2(kq + kk, tx << 2)];
#pragma unroll
            for (int i = 0; i < 8; ++i) {
                qacc[i][0] = fmaf(av[i].x, bm[0].x, fmaf(av[i].y, bm[1].x,
                             fmaf(av[i].z, bm[2].x, fmaf(av[i].w, bm[3].x, qacc[i][0]))));
                qacc[i][1] = fmaf(av[i].x, bm[0].y, fmaf(av[i].y, bm[1].y,
                             fmaf(av[i].z, bm[2].y, fmaf(av[i].w, bm[3].y, qacc[i][1]))));
                qacc[i][2] = fmaf(av[i].x, bm[0].z, fmaf(av[i].y, bm[1].z,
                             fmaf(av[i].z, bm[2].z, fmaf(av[i].w, bm[3].z, qacc[i][2]))));
                qacc[i][3] = fmaf(av[i].x, bm[0].w, fmaf(av[i].y, bm[1].w,
                             fmaf(av[i].z, bm[2].w, fmaf(av[i].w, bm[3].w, qacc[i][3]))));
            }
        }
#pragma unroll
        for (int i = 0; i < 8; ++i) {
            float4 o;
            o.x = qacc[i][0] * 0.125f; o.y = qacc[i][1] * 0.125f;
            o.z = qacc[i][2] * 0.125f; o.w = qacc[i][3] * 0.125f;
            *(float4*)&Qs[swz2((ty << 3) + i, tx << 2)] = o;
        }
    }

    // ---- main flash loop -------------------------------------------------
    float acc[8][4] = {};
    float mi[8], li[8];
#pragma unroll
    for (int i = 0; i < 8; ++i) { mi[i] = -INFINITY; li[i] = 0.f; }

    const int j0max = (qt << 1) + 1;
    for (int j0 = 0; j0 <= j0max; ++j0) {
        __syncthreads();   // prev PV / prologue reads done with Ks/Es
        stage_sw2(pb + (size_t)(j0 << 6) * KD_, Ks, tid, 1024);
        __syncthreads();

        // S = Qs @ Ks^T   (128x64, micro 8x4)
        float s[8][4] = {};
#pragma unroll
        for (int kq = 0; kq < 64; kq += 4) {
            float4 bv[4];
#pragma unroll
            for (int j = 0; j < 4; ++j) bv[j] = *(const float4*)&Ks[swz2((tx << 2) + j, kq)];
#pragma unroll
            for (int i = 0; i < 8; ++i) {
                float4 a = *(const float4*)&Qs[swz2((ty << 3) + i, kq)];
#pragma unroll
                for (int j = 0; j < 4; ++j)
                    s[i][j] = fmaf(a.x, bv[j].x, fmaf(a.y, bv[j].y,
                              fmaf(a.z, bv[j].z, fmaf(a.w, bv[j].w, s[i][j]))));
            }
        }

        if (j0 >= (qt << 1)) {           // diagonal tiles: mask col > row
            int cbase = (j0 << 6) - (qt << 7) + (tx << 2);
#pragma unroll
            for (int i = 0; i < 8; ++i)
#pragma unroll
                for (int j = 0; j < 4; ++j)
                    if (cbase + j > (ty << 3) + i) s[i][j] = -INFINITY;
        }

#pragma unroll
        for (int i = 0; i < 8; ++i) {
            float rm = fmaxf(fmaxf(s[i][0], s[i][1]), fmaxf(s[i][2], s[i][3]));
            rm = fmaxf(rm, __shfl_xor(rm, 1, 16));
            rm = fmaxf(rm, __shfl_xor(rm, 2, 16));
            rm = fmaxf(rm, __shfl_xor(rm, 4, 16));
            rm = fmaxf(rm, __shfl_xor(rm, 8, 16));
            float mnew = fmaxf(mi[i], rm);
#pragma unroll
            for (int j = 0; j < 4; ++j) s[i][j] = __expf(s[i][j] - mnew);
            float rs = s[i][0] + s[i][1] + s[i][2] + s[i][3];
            rs += __shfl_xor(rs, 1, 16);
            rs += __shfl_xor(rs, 2, 16);
            rs += __shfl_xor(rs, 4, 16);
            rs += __shfl_xor(rs, 8, 16);
            float al = __expf(mi[i] - mnew);
            li[i] = li[i] * al + rs;
            mi[i] = mnew;
            float4 e; e.x = s[i][0]; e.y = s[i][1]; e.z = s[i][2]; e.w = s[i][3];
            *(float4*)&Es[swz2((ty << 3) + i, tx << 2)] = e;
#pragma unroll
            for (int j = 0; j < 4; ++j) acc[i][j] *= al;
        }
        __syncthreads();

        // O += Es @ Ks   (V = K tile)
#pragma unroll
        for (int jq = 0; jq < 64; jq += 4) {
            float4 vm[4];
#pragma unroll
            for (int kk = 0; kk < 4; ++kk) vm[kk] = *(const float4*)&Ks[swz2(jq + kk, tx << 2)];
#pragma unroll
            for (int i = 0; i < 8; ++i) {
                float4 a = *(const float4*)&Es[swz2((ty << 3) + i, jq)];
                acc[i][0] = fmaf(a.x, vm[0].x, fmaf(a.y, vm[1].x,
                            fmaf(a.z, vm[2].x, fmaf(a.w, vm[3].x, acc[i][0]))));
                acc[i][1] = fmaf(a.x, vm[0].y, fmaf(a.y, vm[1].y,
                            fmaf(a.z, vm[2].y, fmaf(a.w, vm[3].y, acc[i][1]))));
                acc[i][2] = fmaf(a.x, vm[0].z, fmaf(a.y, vm[1].z,
                            fmaf(a.z, vm[2].z, fmaf(a.w, vm[3].z, acc[i][2]))));
                acc[i][3] = fmaf(a.x, vm[0].w, fmaf(a.y, vm[1].w,
                            fmaf(a.z, vm[2].w, fmaf(a.w, vm[3].w, acc[i][3]))));
            }
        }
    }

    const int wrow = qt << 7;
#pragma unroll
    for (int i = 0; i < 8; ++i) {
        float inv = 1.f / li[i];
        float4 o;
        o.x = acc[i][0] * inv; o.y = acc[i][1] * inv;
        o.z = acc[i][2] * inv; o.w = acc[i][3] * inv;
        size_t row = (size_t)(b * W_ + wrow + (ty << 3) + i);
        *(float4*)(nud + row * C_ + (n << 6) + (tx << 2)) = o;
    }
}

// ---------------------------------------------------------------------------
extern "C" void kernel_launch(void* const* d_in, const int* in_sizes, int n_in,
                              void* d_out, int out_size, void* d_ws, size_t ws_size,
                              hipStream_t stream)
{
    (void)in_sizes; (void)n_in; (void)out_size; (void)ws_size;
    const float* X  = (const float*)d_in[0];
    const float* Wp = (const float*)d_in[1];
    const float* bp = (const float*)d_in[2];
    const float* G  = (const float*)d_in[3];
    const float* Wm = (const float*)d_in[4];
    const float* bm = (const float*)d_in[5];
    float* out = (float*)d_out;
    float* ws  = (float*)d_ws;

    float* Pbuf = ws;                // [bn][w][k]  16 MB
    float* Part = ws + 4194304;      // 32*8*4096 floats (metric partials)
    float* M2   = ws + 8388608;      // [bn][64][64]
    float* Nud  = ws + 8519680;      // [b*W+w][c]  16 MB

    dim3 blk(256);
    gemm128<1>   <<<dim3(32, 8), blk, 0, stream>>>(X, Wp, bp, Pbuf);
    metric_part  <<<dim3(8, 32), blk, 0, stream>>>(Pbuf, G, Part);
    metric_reduce<<<dim3(32),    blk, 0, stream>>>(Part, M2);
    attn_k2      <<<dim3(512),   blk, 0, stream>>>(Pbuf, M2, Nud);
    gemm128<0>   <<<dim3(32, 8), blk, 0, stream>>>(Nud, Wm, bm, out);
}

// Round 5
// 978.714 us; speedup vs baseline: 1.5444x; 1.5444x over previous
//
#include <hip/hip_runtime.h>
#include <math.h>

#define B_  2
#define W_  2048
#define C_  1024
#define NH_ 16
#define KD_ 64

// ---------------------------------------------------------------------------
// XOR-swizzled 64x64 fp32 tile in flat float[4096]. float4 chunk q of row r
// at slot q ^ ((r>>2)&7): strided-row (stride-4) b128 reads are 2-way (free).
// ---------------------------------------------------------------------------
__device__ __forceinline__ int swz2(int r, int c) {
    return (r << 6) + ((((c >> 2) ^ ((r >> 2) & 7)) << 2) | (c & 3));
}
__device__ __forceinline__ void stage_sw2(const float* __restrict__ src,
                                          float* dst, int tid, int nf4) {
    for (int idx = tid; idx < nf4; idx += 256) {
        int r = idx >> 4;
        int c = (idx & 15) << 2;
        *(float4*)&dst[swz2(r, c)] = *(const float4*)(src + (idx << 2));
    }
}

// ---------------------------------------------------------------------------
// GEMM NT (R1/R2-proven, ~80us): C[m,c] = sum_k A[m,k]*Bw[c,k] + bias[c]
// 64x64 tile, 4x4 micro. Grid (64,16).
// ---------------------------------------------------------------------------
template<int OUT_P_LAYOUT>
__global__ __launch_bounds__(256, 2)
void gemm_nt(const float* __restrict__ A, const float* __restrict__ Bw,
             const float* __restrict__ bias, float* __restrict__ Cout)
{
    __shared__ float As[16][68];
    __shared__ float Bs[16][68];
    const int tid = threadIdx.x;
    const int tx  = tid & 15, ty = tid >> 4;
    const int m0  = blockIdx.x << 6;
    const int n0  = blockIdx.y << 6;
    const int lrow = tid >> 2;
    const int lkq  = (tid & 3) << 2;
    const float* Ap = A  + (size_t)(m0 + lrow) * C_ + lkq;
    const float* Bp = Bw + (size_t)(n0 + lrow) * C_ + lkq;

    float acc[4][4] = {};
    for (int k0 = 0; k0 < C_; k0 += 16) {
        float4 av = *(const float4*)(Ap + k0);
        float4 bv = *(const float4*)(Bp + k0);
        __syncthreads();
        As[lkq+0][lrow] = av.x; As[lkq+1][lrow] = av.y;
        As[lkq+2][lrow] = av.z; As[lkq+3][lrow] = av.w;
        Bs[lkq+0][lrow] = bv.x; Bs[lkq+1][lrow] = bv.y;
        Bs[lkq+2][lrow] = bv.z; Bs[lkq+3][lrow] = bv.w;
        __syncthreads();
#pragma unroll
        for (int kk = 0; kk < 16; ++kk) {
            float4 a4 = *(const float4*)&As[kk][ty << 2];
            float4 b4 = *(const float4*)&Bs[kk][tx << 2];
            float am[4] = {a4.x, a4.y, a4.z, a4.w};
            float bm[4] = {b4.x, b4.y, b4.z, b4.w};
#pragma unroll
            for (int i = 0; i < 4; ++i)
#pragma unroll
                for (int j = 0; j < 4; ++j)
                    acc[i][j] = fmaf(am[i], bm[j], acc[i][j]);
        }
    }

    const int gc = n0 + (tx << 2);
    float4 bb = *(const float4*)&bias[gc];
#pragma unroll
    for (int i = 0; i < 4; ++i) {
        int gm = m0 + (ty << 2) + i;
        float4 o;
        o.x = acc[i][0] + bb.x;
        o.y = acc[i][1] + bb.y;
        o.z = acc[i][2] + bb.z;
        o.w = acc[i][3] + bb.w;
        if (OUT_P_LAYOUT) {
            int b = gm >> 11;
            int w = gm & 2047;
            int n = gc >> 6;
            int k = gc & 63;
            *(float4*)(Cout + (((size_t)(b * NH_ + n) * W_ + w) * KD_ + k)) = o;
        } else {
            *(float4*)(Cout + (size_t)gm * C_ + gc) = o;
        }
    }
}

// ---------------------------------------------------------------------------
// metric_part: partial M1[k][l] = sum_{w in chunk} p[bn][w][k]*g[n][w][l]
// Grid (8,32).
// ---------------------------------------------------------------------------
__global__ __launch_bounds__(256, 2)
void metric_part(const float* __restrict__ p, const float* __restrict__ g,
                 float* __restrict__ part)
{
    __shared__ float Ps[32][68];
    __shared__ float Gs[32][68];
    const int ch  = blockIdx.x;
    const int bn  = blockIdx.y;
    const int n   = bn & (NH_ - 1);
    const int tid = threadIdx.x;
    const int tx  = tid & 15, ty = tid >> 4;
    const float* pb = p + (size_t)bn * W_ * KD_ + (size_t)(ch << 8) * KD_;
    const float* gb = g + (size_t)n  * W_ * KD_ + (size_t)(ch << 8) * KD_;

    float acc[4][4] = {};
    for (int w0 = 0; w0 < 256; w0 += 32) {
        __syncthreads();
#pragma unroll
        for (int q = 0; q < 2; ++q) {
            int idx = tid + (q << 8);
            int e   = idx << 2;
            int r   = e >> 6;
            int c   = e & 63;
            *(float4*)&Ps[r][c] = *(const float4*)(pb + (size_t)(w0 + r) * KD_ + c);
            *(float4*)&Gs[r][c] = *(const float4*)(gb + (size_t)(w0 + r) * KD_ + c);
        }
        __syncthreads();
#pragma unroll 8
        for (int w = 0; w < 32; ++w) {
            float4 a4 = *(const float4*)&Ps[w][ty << 2];
            float4 b4 = *(const float4*)&Gs[w][tx << 2];
            float am[4] = {a4.x, a4.y, a4.z, a4.w};
            float bm[4] = {b4.x, b4.y, b4.z, b4.w};
#pragma unroll
            for (int i = 0; i < 4; ++i)
#pragma unroll
                for (int j = 0; j < 4; ++j)
                    acc[i][j] = fmaf(am[i], bm[j], acc[i][j]);
        }
    }

    float* ob = part + (size_t)(bn * 8 + ch) * KD_ * KD_;
#pragma unroll
    for (int i = 0; i < 4; ++i) {
        float4 o; o.x = acc[i][0]; o.y = acc[i][1]; o.z = acc[i][2]; o.w = acc[i][3];
        *(float4*)(ob + ((ty << 2) + i) * KD_ + (tx << 2)) = o;
    }
}

// ---------------------------------------------------------------------------
// metric_reduce: M1 = tril(sum_ch part);  M2 = M1 @ M1^T.  Grid 32.
// ---------------------------------------------------------------------------
__global__ __launch_bounds__(256, 2)
void metric_reduce(const float* __restrict__ part, float* __restrict__ m2)
{
    __shared__ float M1s[64][68];
    const int bn  = blockIdx.x;
    const int tid = threadIdx.x;
    const int tx  = tid & 15, ty = tid >> 4;
    const float* pb = part + (size_t)bn * 8 * KD_ * KD_;

#pragma unroll
    for (int v = 0; v < 4; ++v) {
        int f = tid + (v << 8);
        int e = f << 2;
        float4 s = *(const float4*)(pb + e);
#pragma unroll
        for (int c = 1; c < 8; ++c) {
            float4 t = *(const float4*)(pb + c * 4096 + e);
            s.x += t.x; s.y += t.y; s.z += t.z; s.w += t.w;
        }
        int k = e >> 6, l = e & 63;
        if (l + 0 > k) s.x = 0.f;
        if (l + 1 > k) s.y = 0.f;
        if (l + 2 > k) s.z = 0.f;
        if (l + 3 > k) s.w = 0.f;
        *(float4*)&M1s[k][l] = s;
    }
    __syncthreads();

    float a2[4][4] = {};
#pragma unroll
    for (int jq = 0; jq < 64; jq += 4) {
        float4 av[4], bv[4];
#pragma unroll
        for (int i = 0; i < 4; ++i) av[i] = *(const float4*)&M1s[(ty << 2) + i][jq];
#pragma unroll
        for (int j = 0; j < 4; ++j) bv[j] = *(const float4*)&M1s[(tx << 2) + j][jq];
#pragma unroll
        for (int i = 0; i < 4; ++i)
#pragma unroll
            for (int j = 0; j < 4; ++j)
                a2[i][j] += av[i].x * bv[j].x + av[i].y * bv[j].y +
                            av[i].z * bv[j].z + av[i].w * bv[j].w;
    }

    float* ob = m2 + (size_t)bn * KD_ * KD_;
#pragma unroll
    for (int i = 0; i < 4; ++i) {
        float4 o; o.x = a2[i][0]; o.y = a2[i][1]; o.z = a2[i][2]; o.w = a2[i][3];
        *(float4*)(ob + ((ty << 2) + i) * KD_ + (tx << 2)) = o;
    }
}

// ---------------------------------------------------------------------------
// Q[bn][w][l] = (1/8) * sum_k p[bn][w][k] * M2[bn][k][l]   Grid (32,32).
// ---------------------------------------------------------------------------
__global__ __launch_bounds__(256, 2)
void qgen_k(const float* __restrict__ p, const float* __restrict__ m2,
            float* __restrict__ qout)
{
    __shared__ float Pt[64][68];
    __shared__ float Ms[64][68];
    const int bn  = blockIdx.y;
    const int w0  = blockIdx.x << 6;
    const int tid = threadIdx.x;
    const int tx  = tid & 15, ty = tid >> 4;
    const float* pb = p  + (size_t)bn * W_ * KD_ + (size_t)w0 * KD_;
    const float* mb = m2 + (size_t)bn * KD_ * KD_;

#pragma unroll
    for (int q = 0; q < 4; ++q) {
        int idx = tid + (q << 8);
        int e   = idx << 2;
        int r   = e >> 6;
        int c   = e & 63;
        *(float4*)&Pt[r][c] = *(const float4*)(pb + e);
        *(float4*)&Ms[r][c] = *(const float4*)(mb + e);
    }
    __syncthreads();

    float acc[4][4] = {};
#pragma unroll
    for (int kq = 0; kq < 64; kq += 4) {
        float4 av[4];
        float  bm[4][4];
#pragma unroll
        for (int i = 0; i < 4; ++i) av[i] = *(const float4*)&Pt[(ty << 2) + i][kq];
#pragma unroll
        for (int kk = 0; kk < 4; ++kk) {
            float4 t = *(const float4*)&Ms[kq + kk][tx << 2];
            bm[kk][0] = t.x; bm[kk][1] = t.y; bm[kk][2] = t.z; bm[kk][3] = t.w;
        }
#pragma unroll
        for (int i = 0; i < 4; ++i) {
            float am[4] = {av[i].x, av[i].y, av[i].z, av[i].w};
#pragma unroll
            for (int j = 0; j < 4; ++j)
                acc[i][j] = fmaf(am[0], bm[0][j],
                            fmaf(am[1], bm[1][j],
                            fmaf(am[2], bm[2][j],
                            fmaf(am[3], bm[3][j], acc[i][j]))));
        }
    }

    float* ob = qout + (size_t)bn * W_ * KD_ + (size_t)w0 * KD_;
#pragma unroll
    for (int i = 0; i < 4; ++i) {
        float4 o;
        o.x = acc[i][0] * 0.125f; o.y = acc[i][1] * 0.125f;
        o.z = acc[i][2] * 0.125f; o.w = acc[i][3] * 0.125f;
        *(float4*)(ob + ((ty << 2) + i) * KD_ + (tx << 2)) = o;
    }
}

// ---------------------------------------------------------------------------
// Chunked causal flash attention. q-tile 64, micro 4x4, 48KB LDS (3 blk/CU).
// mode 0 (fallback): bid -> bn=bid&31, qt=31-(bid>>5), full k-range, direct
//   write (grid 1024).
// mode 1 (k-split): cid=59-(bid>>5); chunks of <=12 k-tiles. qt<12: single
//   chunk, direct write. qt>=12: write partial (O unnorm, m, l) to
//   part[slot=bn*60+cid][4224]; combine_k merges (grid 1920).
// ---------------------------------------------------------------------------
__global__ __launch_bounds__(256, 2)
void attn_ck(const float* __restrict__ qg, const float* __restrict__ p,
             float* __restrict__ nud, float* __restrict__ part, int mode)
{
    __shared__ float Qs[4096];
    __shared__ float Ks[4096];
    __shared__ float Es[4096];
    const int bid = blockIdx.x;
    const int bn  = bid & 31;
    const int b   = bn >> 4, n = bn & 15;
    const int tid = threadIdx.x;
    const int tx  = tid & 15, ty = tid >> 4;

    int qt, js, je, direct, slot = 0;
    if (mode == 0) {
        int cid = bid >> 5;
        qt = 31 - cid; js = 0; je = qt + 1; direct = 1;
    } else {
        int cid = 59 - (bid >> 5);         // descending-cost-ish dispatch
        int c0;
        if (cid < 12)      { qt = cid;                c0 = 0; }
        else if (cid < 36) { qt = 12 + ((cid-12)>>1); c0 = (cid-12)&1; }
        else               { qt = 24 + (cid-36)/3;    c0 = (cid-36)%3; }
        js = c0 * 12;
        je = min(js + 12, qt + 1);
        direct = (qt < 12);
        slot = bn * 60 + cid;
    }

    const float* pb = p + (size_t)bn * W_ * KD_;
    stage_sw2(qg + (size_t)bn * W_ * KD_ + (size_t)(qt << 6) * KD_, Qs, tid, 1024);

    float acc[4][4] = {};
    float mi[4], li[4];
#pragma unroll
    for (int i = 0; i < 4; ++i) { mi[i] = -INFINITY; li[i] = 0.f; }

    for (int j0 = js; j0 < je; ++j0) {
        __syncthreads();   // prev PV done with Ks/Es; also covers Qs staging
        stage_sw2(pb + (size_t)(j0 << 6) * KD_, Ks, tid, 1024);
        __syncthreads();

        // S = Qs @ Ks^T
        float s[4][4] = {};
#pragma unroll
        for (int kq = 0; kq < 64; kq += 4) {
            float4 av[4], bv[4];
#pragma unroll
            for (int i = 0; i < 4; ++i) av[i] = *(const float4*)&Qs[swz2((ty << 2) + i, kq)];
#pragma unroll
            for (int j = 0; j < 4; ++j) bv[j] = *(const float4*)&Ks[swz2((tx << 2) + j, kq)];
#pragma unroll
            for (int i = 0; i < 4; ++i)
#pragma unroll
                for (int j = 0; j < 4; ++j)
                    s[i][j] = fmaf(av[i].x, bv[j].x,
                              fmaf(av[i].y, bv[j].y,
                              fmaf(av[i].z, bv[j].z,
                              fmaf(av[i].w, bv[j].w, s[i][j]))));
        }

        if (j0 == qt) {      // diagonal tile: mask col > row
#pragma unroll
            for (int i = 0; i < 4; ++i)
#pragma unroll
                for (int j = 0; j < 4; ++j)
                    if (((tx << 2) + j) > ((ty << 2) + i)) s[i][j] = -INFINITY;
        }

#pragma unroll
        for (int i = 0; i < 4; ++i) {
            float rm = fmaxf(fmaxf(s[i][0], s[i][1]), fmaxf(s[i][2], s[i][3]));
            rm = fmaxf(rm, __shfl_xor(rm, 1, 16));
            rm = fmaxf(rm, __shfl_xor(rm, 2, 16));
            rm = fmaxf(rm, __shfl_xor(rm, 4, 16));
            rm = fmaxf(rm, __shfl_xor(rm, 8, 16));
            float mnew = fmaxf(mi[i], rm);
#pragma unroll
            for (int j = 0; j < 4; ++j) s[i][j] = __expf(s[i][j] - mnew);
            float rs = s[i][0] + s[i][1] + s[i][2] + s[i][3];
            rs += __shfl_xor(rs, 1, 16);
            rs += __shfl_xor(rs, 2, 16);
            rs += __shfl_xor(rs, 4, 16);
            rs += __shfl_xor(rs, 8, 16);
            float al = __expf(mi[i] - mnew);
            li[i] = li[i] * al + rs;
            mi[i] = mnew;
            float4 e; e.x = s[i][0]; e.y = s[i][1]; e.z = s[i][2]; e.w = s[i][3];
            *(float4*)&Es[swz2((ty << 2) + i, tx << 2)] = e;
#pragma unroll
            for (int j = 0; j < 4; ++j) acc[i][j] *= al;
        }
        __syncthreads();

        // O += Es @ Ks  (V = K tile)
#pragma unroll
        for (int jq = 0; jq < 64; jq += 4) {
            float4 vm[4];
#pragma unroll
            for (int kk = 0; kk < 4; ++kk) vm[kk] = *(const float4*)&Ks[swz2(jq + kk, tx << 2)];
#pragma unroll
            for (int i = 0; i < 4; ++i) {
                float4 a = *(const float4*)&Es[swz2((ty << 2) + i, jq)];
                acc[i][0] = fmaf(a.x, vm[0].x, fmaf(a.y, vm[1].x,
                            fmaf(a.z, vm[2].x, fmaf(a.w, vm[3].x, acc[i][0]))));
                acc[i][1] = fmaf(a.x, vm[0].y, fmaf(a.y, vm[1].y,
                            fmaf(a.z, vm[2].y, fmaf(a.w, vm[3].y, acc[i][1]))));
                acc[i][2] = fmaf(a.x, vm[0].z, fmaf(a.y, vm[1].z,
                            fmaf(a.z, vm[2].z, fmaf(a.w, vm[3].z, acc[i][2]))));
                acc[i][3] = fmaf(a.x, vm[0].w, fmaf(a.y, vm[1].w,
                            fmaf(a.z, vm[2].w, fmaf(a.w, vm[3].w, acc[i][3]))));
            }
        }
    }

    if (direct) {
        const int wrow = qt << 6;
#pragma unroll
        for (int i = 0; i < 4; ++i) {
            float inv = 1.f / li[i];
            float4 o;
            o.x = acc[i][0] * inv; o.y = acc[i][1] * inv;
            o.z = acc[i][2] * inv; o.w = acc[i][3] * inv;
            size_t row = (size_t)(b * W_ + wrow + (ty << 2) + i);
            *(float4*)(nud + row * C_ + (n << 6) + (tx << 2)) = o;
        }
    } else {
        float* ob = part + (size_t)slot * 4224;
#pragma unroll
        for (int i = 0; i < 4; ++i) {
            int r = (ty << 2) + i;
            float4 o;
            o.x = acc[i][0]; o.y = acc[i][1]; o.z = acc[i][2]; o.w = acc[i][3];
            *(float4*)(ob + (r << 6) + (tx << 2)) = o;
            if (tx == 0) {
                ob[4096 + r] = mi[i];
                ob[4160 + r] = li[i];
            }
        }
    }
}

// ---------------------------------------------------------------------------
// combine_k: merge k-split partials for qt>=12 q-tiles. Grid 640.
// ---------------------------------------------------------------------------
__global__ __launch_bounds__(256, 2)
void combine_k(const float* __restrict__ part, float* __restrict__ nud)
{
    const int bid = blockIdx.x;
    const int bn  = bid & 31;
    const int qt  = 12 + (bid >> 5);        // 12..31
    const int b   = bn >> 4, n = bn & 15;
    int nc, cid0;
    if (qt < 24) { nc = 2; cid0 = 12 + ((qt - 12) << 1); }
    else         { nc = 3; cid0 = 36 + 3 * (qt - 24); }
    const float* p0 = part + (size_t)(bn * 60 + cid0) * 4224;
    const int tid = threadIdx.x;

#pragma unroll
    for (int k = 0; k < 4; ++k) {
        int f4 = tid + (k << 8);
        int e  = f4 << 2;
        int r  = e >> 6;
        float M = -INFINITY;
        for (int c = 0; c < nc; ++c)
            M = fmaxf(M, p0[c * 4224 + 4096 + r]);
        float Ox = 0.f, Oy = 0.f, Oz = 0.f, Ow = 0.f, L = 0.f;
        for (int c = 0; c < nc; ++c) {
            float w = __expf(p0[c * 4224 + 4096 + r] - M);
            float4 t = *(const float4*)(p0 + c * 4224 + e);
            Ox += w * t.x; Oy += w * t.y; Oz += w * t.z; Ow += w * t.w;
            L  += w * p0[c * 4224 + 4160 + r];
        }
        float inv = 1.f / L;
        float4 o; o.x = Ox * inv; o.y = Oy * inv; o.z = Oz * inv; o.w = Ow * inv;
        size_t row = (size_t)(b * W_ + (qt << 6) + r);
        *(float4*)(nud + row * C_ + (n << 6) + (e & 63)) = o;
    }
}

// ---------------------------------------------------------------------------
extern "C" void kernel_launch(void* const* d_in, const int* in_sizes, int n_in,
                              void* d_out, int out_size, void* d_ws, size_t ws_size,
                              hipStream_t stream)
{
    (void)in_sizes; (void)n_in; (void)out_size;
    const float* X  = (const float*)d_in[0];
    const float* Wp = (const float*)d_in[1];
    const float* bp = (const float*)d_in[2];
    const float* G  = (const float*)d_in[3];
    const float* Wm = (const float*)d_in[4];
    const float* bm = (const float*)d_in[5];
    float* out = (float*)d_out;
    float* ws  = (float*)d_ws;

    float* Pbuf  = ws;                 // [bn][w][k]       16 MB
    float* Qbuf  = ws + 4194304;       // [bn][w][k]       16 MB
    float* M2    = ws + 8388608;       // [bn][64][64]     0.5 MB
    float* Nud   = ws + 8519680;       // [b*W+w][c]       16 MB
    float* Part2 = ws + 12713984;      // 1920 x 4224      32.4 MB (k-split partials)

    // ws budget check (deterministic per process -> graph-capture safe)
    const size_t needF = 12713984ULL + 1920ULL * 4224ULL;
    const bool big = ws_size >= needF * sizeof(float);
    // metric partials (1,048,576 floats) overlay a later-dead region:
    float* MPart = big ? Part2 : Nud;

    dim3 blk(256);
    gemm_nt<1>   <<<dim3(64, 16), blk, 0, stream>>>(X, Wp, bp, Pbuf);
    metric_part  <<<dim3(8, 32),  blk, 0, stream>>>(Pbuf, G, MPart);
    metric_reduce<<<dim3(32),     blk, 0, stream>>>(MPart, M2);
    qgen_k       <<<dim3(32, 32), blk, 0, stream>>>(Pbuf, M2, Qbuf);
    if (big) {
        attn_ck  <<<dim3(1920),   blk, 0, stream>>>(Qbuf, Pbuf, Nud, Part2, 1);
        combine_k<<<dim3(640),    blk, 0, stream>>>(Part2, Nud);
    } else {
        attn_ck  <<<dim3(1024),   blk, 0, stream>>>(Qbuf, Pbuf, Nud, Part2, 0);
    }
    gemm_nt<0>   <<<dim3(64, 16), blk, 0, stream>>>(Nud, Wm, bm, out);
}

// Round 6
// 920.495 us; speedup vs baseline: 1.6420x; 1.0632x over previous
//
#include <hip/hip_runtime.h>
#include <math.h>

#define B_  2
#define W_  2048
#define C_  1024
#define NH_ 16
#define KD_ 64

// ---------------------------------------------------------------------------
// XOR-swizzled 64x64 fp32 tile in flat float[4096]. float4 chunk q of row r
// at slot q ^ ((r>>2)&7): strided-row (stride-4) b128 reads are 2-way (free).
// ---------------------------------------------------------------------------
__device__ __forceinline__ int swz2(int r, int c) {
    return (r << 6) + ((((c >> 2) ^ ((r >> 2) & 7)) << 2) | (c & 3));
}
__device__ __forceinline__ void stage_sw2(const float* __restrict__ src,
                                          float* dst, int tid, int nf4) {
    for (int idx = tid; idx < nf4; idx += 256) {
        int r = idx >> 4;
        int c = (idx & 15) << 2;
        *(float4*)&dst[swz2(r, c)] = *(const float4*)(src + (idx << 2));
    }
}

// ---------------------------------------------------------------------------
// GEMM NT (proven ~80us): C[m,c] = sum_k A[m,k]*Bw[c,k] + bias[c]
// 64x64 tile, 4x4 micro, register-prefetched staging. Grid (64,16).
// ---------------------------------------------------------------------------
template<int OUT_P_LAYOUT>
__global__ __launch_bounds__(256, 2)
void gemm_nt(const float* __restrict__ A, const float* __restrict__ Bw,
             const float* __restrict__ bias, float* __restrict__ Cout)
{
    __shared__ float As[16][68];
    __shared__ float Bs[16][68];
    const int tid = threadIdx.x;
    const int tx  = tid & 15, ty = tid >> 4;
    const int m0  = blockIdx.x << 6;
    const int n0  = blockIdx.y << 6;
    const int lrow = tid >> 2;
    const int lkq  = (tid & 3) << 2;
    const float* Ap = A  + (size_t)(m0 + lrow) * C_ + lkq;
    const float* Bp = Bw + (size_t)(n0 + lrow) * C_ + lkq;

    float acc[4][4] = {};
    for (int k0 = 0; k0 < C_; k0 += 16) {
        float4 av = *(const float4*)(Ap + k0);
        float4 bv = *(const float4*)(Bp + k0);
        __syncthreads();
        As[lkq+0][lrow] = av.x; As[lkq+1][lrow] = av.y;
        As[lkq+2][lrow] = av.z; As[lkq+3][lrow] = av.w;
        Bs[lkq+0][lrow] = bv.x; Bs[lkq+1][lrow] = bv.y;
        Bs[lkq+2][lrow] = bv.z; Bs[lkq+3][lrow] = bv.w;
        __syncthreads();
#pragma unroll
        for (int kk = 0; kk < 16; ++kk) {
            float4 a4 = *(const float4*)&As[kk][ty << 2];
            float4 b4 = *(const float4*)&Bs[kk][tx << 2];
            float am[4] = {a4.x, a4.y, a4.z, a4.w};
            float bm[4] = {b4.x, b4.y, b4.z, b4.w};
#pragma unroll
            for (int i = 0; i < 4; ++i)
#pragma unroll
                for (int j = 0; j < 4; ++j)
                    acc[i][j] = fmaf(am[i], bm[j], acc[i][j]);
        }
    }

    const int gc = n0 + (tx << 2);
    float4 bb = *(const float4*)&bias[gc];
#pragma unroll
    for (int i = 0; i < 4; ++i) {
        int gm = m0 + (ty << 2) + i;
        float4 o;
        o.x = acc[i][0] + bb.x;
        o.y = acc[i][1] + bb.y;
        o.z = acc[i][2] + bb.z;
        o.w = acc[i][3] + bb.w;
        if (OUT_P_LAYOUT) {
            int b = gm >> 11;
            int w = gm & 2047;
            int n = gc >> 6;
            int k = gc & 63;
            *(float4*)(Cout + (((size_t)(b * NH_ + n) * W_ + w) * KD_ + k)) = o;
        } else {
            *(float4*)(Cout + (size_t)gm * C_ + gc) = o;
        }
    }
}

// ---------------------------------------------------------------------------
// metric_part: partial M1[k][l] = sum_{w in chunk} p[bn][w][k]*g[n][w][l]
// Grid (8,32).  Register-prefetched staging.
// ---------------------------------------------------------------------------
__global__ __launch_bounds__(256, 2)
void metric_part(const float* __restrict__ p, const float* __restrict__ g,
                 float* __restrict__ part)
{
    __shared__ float Ps[32][68];
    __shared__ float Gs[32][68];
    const int ch  = blockIdx.x;
    const int bn  = blockIdx.y;
    const int n   = bn & (NH_ - 1);
    const int tid = threadIdx.x;
    const int tx  = tid & 15, ty = tid >> 4;
    const float* pb = p + (size_t)bn * W_ * KD_ + (size_t)(ch << 8) * KD_;
    const float* gb = g + (size_t)n  * W_ * KD_ + (size_t)(ch << 8) * KD_;

    int r0[2], c0[2];
#pragma unroll
    for (int q = 0; q < 2; ++q) {
        int idx = tid + (q << 8);
        r0[q] = (idx << 2) >> 6;
        c0[q] = (idx << 2) & 63;
    }
    float4 rp[2], rg[2];
#pragma unroll
    for (int q = 0; q < 2; ++q) {
        rp[q] = *(const float4*)(pb + (size_t)r0[q] * KD_ + c0[q]);
        rg[q] = *(const float4*)(gb + (size_t)r0[q] * KD_ + c0[q]);
    }

    float acc[4][4] = {};
    for (int w0 = 0; w0 < 256; w0 += 32) {
        __syncthreads();
#pragma unroll
        for (int q = 0; q < 2; ++q) {
            *(float4*)&Ps[r0[q]][c0[q]] = rp[q];
            *(float4*)&Gs[r0[q]][c0[q]] = rg[q];
        }
        __syncthreads();
        if (w0 < 224) {
#pragma unroll
            for (int q = 0; q < 2; ++q) {
                rp[q] = *(const float4*)(pb + (size_t)(w0 + 32 + r0[q]) * KD_ + c0[q]);
                rg[q] = *(const float4*)(gb + (size_t)(w0 + 32 + r0[q]) * KD_ + c0[q]);
            }
        }
#pragma unroll 8
        for (int w = 0; w < 32; ++w) {
            float4 a4 = *(const float4*)&Ps[w][ty << 2];
            float4 b4 = *(const float4*)&Gs[w][tx << 2];
            float am[4] = {a4.x, a4.y, a4.z, a4.w};
            float bm[4] = {b4.x, b4.y, b4.z, b4.w};
#pragma unroll
            for (int i = 0; i < 4; ++i)
#pragma unroll
                for (int j = 0; j < 4; ++j)
                    acc[i][j] = fmaf(am[i], bm[j], acc[i][j]);
        }
    }

    float* ob = part + (size_t)(bn * 8 + ch) * KD_ * KD_;
#pragma unroll
    for (int i = 0; i < 4; ++i) {
        float4 o; o.x = acc[i][0]; o.y = acc[i][1]; o.z = acc[i][2]; o.w = acc[i][3];
        *(float4*)(ob + ((ty << 2) + i) * KD_ + (tx << 2)) = o;
    }
}

// ---------------------------------------------------------------------------
// metric_reduce: M1 = tril(sum_ch part);  M2 = M1 @ M1^T.  Grid 32.
// ---------------------------------------------------------------------------
__global__ __launch_bounds__(256, 2)
void metric_reduce(const float* __restrict__ part, float* __restrict__ m2)
{
    __shared__ float M1s[64][68];
    const int bn  = blockIdx.x;
    const int tid = threadIdx.x;
    const int tx  = tid & 15, ty = tid >> 4;
    const float* pb = part + (size_t)bn * 8 * KD_ * KD_;

#pragma unroll
    for (int v = 0; v < 4; ++v) {
        int f = tid + (v << 8);
        int e = f << 2;
        float4 s = *(const float4*)(pb + e);
#pragma unroll
        for (int c = 1; c < 8; ++c) {
            float4 t = *(const float4*)(pb + c * 4096 + e);
            s.x += t.x; s.y += t.y; s.z += t.z; s.w += t.w;
        }
        int k = e >> 6, l = e & 63;
        if (l + 0 > k) s.x = 0.f;
        if (l + 1 > k) s.y = 0.f;
        if (l + 2 > k) s.z = 0.f;
        if (l + 3 > k) s.w = 0.f;
        *(float4*)&M1s[k][l] = s;
    }
    __syncthreads();

    float a2[4][4] = {};
#pragma unroll
    for (int jq = 0; jq < 64; jq += 4) {
        float4 av[4], bv[4];
#pragma unroll
        for (int i = 0; i < 4; ++i) av[i] = *(const float4*)&M1s[(ty << 2) + i][jq];
#pragma unroll
        for (int j = 0; j < 4; ++j) bv[j] = *(const float4*)&M1s[(tx << 2) + j][jq];
#pragma unroll
        for (int i = 0; i < 4; ++i)
#pragma unroll
            for (int j = 0; j < 4; ++j)
                a2[i][j] += av[i].x * bv[j].x + av[i].y * bv[j].y +
                            av[i].z * bv[j].z + av[i].w * bv[j].w;
    }

    float* ob = m2 + (size_t)bn * KD_ * KD_;
#pragma unroll
    for (int i = 0; i < 4; ++i) {
        float4 o; o.x = a2[i][0]; o.y = a2[i][1]; o.z = a2[i][2]; o.w = a2[i][3];
        *(float4*)(ob + ((ty << 2) + i) * KD_ + (tx << 2)) = o;
    }
}

// ---------------------------------------------------------------------------
// Q[bn][w][l] = (1/8) * sum_k p[bn][w][k] * M2[bn][k][l]   Grid (32,32).
// ---------------------------------------------------------------------------
__global__ __launch_bounds__(256, 2)
void qgen_k(const float* __restrict__ p, const float* __restrict__ m2,
            float* __restrict__ qout)
{
    __shared__ float Pt[64][68];
    __shared__ float Ms[64][68];
    const int bn  = blockIdx.y;
    const int w0  = blockIdx.x << 6;
    const int tid = threadIdx.x;
    const int tx  = tid & 15, ty = tid >> 4;
    const float* pb = p  + (size_t)bn * W_ * KD_ + (size_t)w0 * KD_;
    const float* mb = m2 + (size_t)bn * KD_ * KD_;

#pragma unroll
    for (int q = 0; q < 4; ++q) {
        int idx = tid + (q << 8);
        int e   = idx << 2;
        int r   = e >> 6;
        int c   = e & 63;
        *(float4*)&Pt[r][c] = *(const float4*)(pb + e);
        *(float4*)&Ms[r][c] = *(const float4*)(mb + e);
    }
    __syncthreads();

    float acc[4][4] = {};
#pragma unroll
    for (int kq = 0; kq < 64; kq += 4) {
        float4 av[4];
        float  bm[4][4];
#pragma unroll
        for (int i = 0; i < 4; ++i) av[i] = *(const float4*)&Pt[(ty << 2) + i][kq];
#pragma unroll
        for (int kk = 0; kk < 4; ++kk) {
            float4 t = *(const float4*)&Ms[kq + kk][tx << 2];
            bm[kk][0] = t.x; bm[kk][1] = t.y; bm[kk][2] = t.z; bm[kk][3] = t.w;
        }
#pragma unroll
        for (int i = 0; i < 4; ++i) {
            float am[4] = {av[i].x, av[i].y, av[i].z, av[i].w};
#pragma unroll
            for (int j = 0; j < 4; ++j)
                acc[i][j] = fmaf(am[0], bm[0][j],
                            fmaf(am[1], bm[1][j],
                            fmaf(am[2], bm[2][j],
                            fmaf(am[3], bm[3][j], acc[i][j]))));
        }
    }

    float* ob = qout + (size_t)bn * W_ * KD_ + (size_t)w0 * KD_;
#pragma unroll
    for (int i = 0; i < 4; ++i) {
        float4 o;
        o.x = acc[i][0] * 0.125f; o.y = acc[i][1] * 0.125f;
        o.z = acc[i][2] * 0.125f; o.w = acc[i][3] * 0.125f;
        *(float4*)(ob + ((ty << 2) + i) * KD_ + (tx << 2)) = o;
    }
}

// ---------------------------------------------------------------------------
// Chunked causal flash attention. q-tile 64, micro 4x4, 48KB LDS, 3 blk/CU
// (enforced via __launch_bounds__(256,3): VGPR cap ~170).
// K-tile is register-PREFETCHED one iteration ahead so global latency is
// covered by the S-loop (gemm-proven pattern).
// mode 0: full k-range per q-tile (grid 1024). mode 1: k-split chunks of
// <=12 k-tiles, partials merged by combine_k (grid 1920).
// ---------------------------------------------------------------------------
__global__ __launch_bounds__(256, 3)
void attn_ck(const float* __restrict__ qg, const float* __restrict__ p,
             float* __restrict__ nud, float* __restrict__ part, int mode)
{
    __shared__ float Qs[4096];
    __shared__ float Ks[4096];
    __shared__ float Es[4096];
    const int bid = blockIdx.x;
    const int bn  = bid & 31;
    const int b   = bn >> 4, n = bn & 15;
    const int tid = threadIdx.x;
    const int tx  = tid & 15, ty = tid >> 4;

    int qt, js, je, direct, slot = 0;
    if (mode == 0) {
        int cid = bid >> 5;
        qt = 31 - cid; js = 0; je = qt + 1; direct = 1;
    } else {
        int cid = 59 - (bid >> 5);         // descending-cost dispatch
        int c0;
        if (cid < 12)      { qt = cid;                c0 = 0; }
        else if (cid < 36) { qt = 12 + ((cid-12)>>1); c0 = (cid-12)&1; }
        else               { qt = 24 + (cid-36)/3;    c0 = (cid-36)%3; }
        js = c0 * 12;
        je = min(js + 12, qt + 1);
        direct = (qt < 12);
        slot = bn * 60 + cid;
    }

    const float* pb = p + (size_t)bn * W_ * KD_;
    stage_sw2(qg + (size_t)bn * W_ * KD_ + (size_t)(qt << 6) * KD_, Qs, tid, 1024);

    // per-thread staging coords + first K-tile prefetch
    int sr[4], sc[4];
#pragma unroll
    for (int t = 0; t < 4; ++t) {
        int idx = tid + (t << 8);
        sr[t] = idx >> 4;
        sc[t] = (idx & 15) << 2;
    }
    float4 pk[4];
    {
        const float* kp = pb + (size_t)(js << 6) * KD_;
#pragma unroll
        for (int t = 0; t < 4; ++t)
            pk[t] = *(const float4*)(kp + ((tid + (t << 8)) << 2));
    }

    float acc[4][4] = {};
    float mi[4], li[4];
#pragma unroll
    for (int i = 0; i < 4; ++i) { mi[i] = -INFINITY; li[i] = 0.f; }

    for (int j0 = js; j0 < je; ++j0) {
        __syncthreads();   // prev PV done with Ks/Es; Qs staged (first iter)
#pragma unroll
        for (int t = 0; t < 4; ++t)
            *(float4*)&Ks[swz2(sr[t], sc[t])] = pk[t];
        __syncthreads();

        // issue next K-tile prefetch (covered by S-loop + softmax)
        if (j0 + 1 < je) {
            const float* np = pb + (size_t)((j0 + 1) << 6) * KD_;
#pragma unroll
            for (int t = 0; t < 4; ++t)
                pk[t] = *(const float4*)(np + ((tid + (t << 8)) << 2));
        }

        // S = Qs @ Ks^T
        float s[4][4] = {};
#pragma unroll
        for (int kq = 0; kq < 64; kq += 4) {
            float4 av[4], bv[4];
#pragma unroll
            for (int i = 0; i < 4; ++i) av[i] = *(const float4*)&Qs[swz2((ty << 2) + i, kq)];
#pragma unroll
            for (int j = 0; j < 4; ++j) bv[j] = *(const float4*)&Ks[swz2((tx << 2) + j, kq)];
#pragma unroll
            for (int i = 0; i < 4; ++i)
#pragma unroll
                for (int j = 0; j < 4; ++j)
                    s[i][j] = fmaf(av[i].x, bv[j].x,
                              fmaf(av[i].y, bv[j].y,
                              fmaf(av[i].z, bv[j].z,
                              fmaf(av[i].w, bv[j].w, s[i][j]))));
        }

        if (j0 == qt) {      // diagonal tile: mask col > row
#pragma unroll
            for (int i = 0; i < 4; ++i)
#pragma unroll
                for (int j = 0; j < 4; ++j)
                    if (((tx << 2) + j) > ((ty << 2) + i)) s[i][j] = -INFINITY;
        }

#pragma unroll
        for (int i = 0; i < 4; ++i) {
            float rm = fmaxf(fmaxf(s[i][0], s[i][1]), fmaxf(s[i][2], s[i][3]));
            rm = fmaxf(rm, __shfl_xor(rm, 1, 16));
            rm = fmaxf(rm, __shfl_xor(rm, 2, 16));
            rm = fmaxf(rm, __shfl_xor(rm, 4, 16));
            rm = fmaxf(rm, __shfl_xor(rm, 8, 16));
            float mnew = fmaxf(mi[i], rm);
#pragma unroll
            for (int j = 0; j < 4; ++j) s[i][j] = __expf(s[i][j] - mnew);
            float rs = s[i][0] + s[i][1] + s[i][2] + s[i][3];
            rs += __shfl_xor(rs, 1, 16);
            rs += __shfl_xor(rs, 2, 16);
            rs += __shfl_xor(rs, 4, 16);
            rs += __shfl_xor(rs, 8, 16);
            float al = __expf(mi[i] - mnew);
            li[i] = li[i] * al + rs;
            mi[i] = mnew;
            float4 e; e.x = s[i][0]; e.y = s[i][1]; e.z = s[i][2]; e.w = s[i][3];
            *(float4*)&Es[swz2((ty << 2) + i, tx << 2)] = e;
#pragma unroll
            for (int j = 0; j < 4; ++j) acc[i][j] *= al;
        }
        __syncthreads();

        // O += Es @ Ks  (V = K tile)
#pragma unroll
        for (int jq = 0; jq < 64; jq += 4) {
            float4 vm[4];
#pragma unroll
            for (int kk = 0; kk < 4; ++kk) vm[kk] = *(const float4*)&Ks[swz2(jq + kk, tx << 2)];
#pragma unroll
            for (int i = 0; i < 4; ++i) {
                float4 a = *(const float4*)&Es[swz2((ty << 2) + i, jq)];
                acc[i][0] = fmaf(a.x, vm[0].x, fmaf(a.y, vm[1].x,
                            fmaf(a.z, vm[2].x, fmaf(a.w, vm[3].x, acc[i][0]))));
                acc[i][1] = fmaf(a.x, vm[0].y, fmaf(a.y, vm[1].y,
                            fmaf(a.z, vm[2].y, fmaf(a.w, vm[3].y, acc[i][1]))));
                acc[i][2] = fmaf(a.x, vm[0].z, fmaf(a.y, vm[1].z,
                            fmaf(a.z, vm[2].z, fmaf(a.w, vm[3].z, acc[i][2]))));
                acc[i][3] = fmaf(a.x, vm[0].w, fmaf(a.y, vm[1].w,
                            fmaf(a.z, vm[2].w, fmaf(a.w, vm[3].w, acc[i][3]))));
            }
        }
    }

    if (direct) {
        const int wrow = qt << 6;
#pragma unroll
        for (int i = 0; i < 4; ++i) {
            float inv = 1.f / li[i];
            float4 o;
            o.x = acc[i][0] * inv; o.y = acc[i][1] * inv;
            o.z = acc[i][2] * inv; o.w = acc[i][3] * inv;
            size_t row = (size_t)(b * W_ + wrow + (ty << 2) + i);
            *(float4*)(nud + row * C_ + (n << 6) + (tx << 2)) = o;
        }
    } else {
        float* ob = part + (size_t)slot * 4224;
#pragma unroll
        for (int i = 0; i < 4; ++i) {
            int r = (ty << 2) + i;
            float4 o;
            o.x = acc[i][0]; o.y = acc[i][1]; o.z = acc[i][2]; o.w = acc[i][3];
            *(float4*)(ob + (r << 6) + (tx << 2)) = o;
            if (tx == 0) {
                ob[4096 + r] = mi[i];
                ob[4160 + r] = li[i];
            }
        }
    }
}

// ---------------------------------------------------------------------------
// combine_k: merge k-split partials for qt>=12 q-tiles. Grid 640.
// ---------------------------------------------------------------------------
__global__ __launch_bounds__(256, 2)
void combine_k(const float* __restrict__ part, float* __restrict__ nud)
{
    const int bid = blockIdx.x;
    const int bn  = bid & 31;
    const int qt  = 12 + (bid >> 5);        // 12..31
    const int b   = bn >> 4, n = bn & 15;
    int nc, cid0;
    if (qt < 24) { nc = 2; cid0 = 12 + ((qt - 12) << 1); }
    else         { nc = 3; cid0 = 36 + 3 * (qt - 24); }
    const float* p0 = part + (size_t)(bn * 60 + cid0) * 4224;
    const int tid = threadIdx.x;

#pragma unroll
    for (int k = 0; k < 4; ++k) {
        int f4 = tid + (k << 8);
        int e  = f4 << 2;
        int r  = e >> 6;
        float M = -INFINITY;
        for (int c = 0; c < nc; ++c)
            M = fmaxf(M, p0[c * 4224 + 4096 + r]);
        float Ox = 0.f, Oy = 0.f, Oz = 0.f, Ow = 0.f, L = 0.f;
        for (int c = 0; c < nc; ++c) {
            float w = __expf(p0[c * 4224 + 4096 + r] - M);
            float4 t = *(const float4*)(p0 + c * 4224 + e);
            Ox += w * t.x; Oy += w * t.y; Oz += w * t.z; Ow += w * t.w;
            L  += w * p0[c * 4224 + 4160 + r];
        }
        float inv = 1.f / L;
        float4 o; o.x = Ox * inv; o.y = Oy * inv; o.z = Oz * inv; o.w = Ow * inv;
        size_t row = (size_t)(b * W_ + (qt << 6) + r);
        *(float4*)(nud + row * C_ + (n << 6) + (e & 63)) = o;
    }
}

// ---------------------------------------------------------------------------
extern "C" void kernel_launch(void* const* d_in, const int* in_sizes, int n_in,
                              void* d_out, int out_size, void* d_ws, size_t ws_size,
                              hipStream_t stream)
{
    (void)in_sizes; (void)n_in; (void)out_size;
    const float* X  = (const float*)d_in[0];
    const float* Wp = (const float*)d_in[1];
    const float* bp = (const float*)d_in[2];
    const float* G  = (const float*)d_in[3];
    const float* Wm = (const float*)d_in[4];
    const float* bm = (const float*)d_in[5];
    float* out = (float*)d_out;
    float* ws  = (float*)d_ws;

    float* Pbuf  = ws;                 // [bn][w][k]       16 MB
    float* Qbuf  = ws + 4194304;       // [bn][w][k]       16 MB
    float* M2    = ws + 8388608;       // [bn][64][64]     0.5 MB
    float* Nud   = ws + 8519680;       // [b*W+w][c]       16 MB
    float* Part2 = ws + 12713984;      // 1920 x 4224      32.4 MB (k-split partials)

    const size_t needF = 12713984ULL + 1920ULL * 4224ULL;
    const bool big = ws_size >= needF * sizeof(float);
    float* MPart = big ? Part2 : Nud;  // metric partials overlay a dead region

    dim3 blk(256);
    gemm_nt<1>   <<<dim3(64, 16), blk, 0, stream>>>(X, Wp, bp, Pbuf);
    metric_part  <<<dim3(8, 32),  blk, 0, stream>>>(Pbuf, G, MPart);
    metric_reduce<<<dim3(32),     blk, 0, stream>>>(MPart, M2);
    qgen_k       <<<dim3(32, 32), blk, 0, stream>>>(Pbuf, M2, Qbuf);
    if (big) {
        attn_ck  <<<dim3(1920),   blk, 0, stream>>>(Qbuf, Pbuf, Nud, Part2, 1);
        combine_k<<<dim3(640),    blk, 0, stream>>>(Part2, Nud);
    } else {
        attn_ck  <<<dim3(1024),   blk, 0, stream>>>(Qbuf, Pbuf, Nud, Part2, 0);
    }
    gemm_nt<0>   <<<dim3(64, 16), blk, 0, stream>>>(Nud, Wm, bm, out);
}